// Round 7
// baseline (98.416 us; speedup 1.0000x reference)
//
#include <hip/hip_runtime.h>
#include <hip/hip_bf16.h>

// FConv2d, round 14 = round-13 kernel + DIAGNOSTIC rep-loop (reps=3).
// Purpose: fconv (<42.6us) never enters rocprof top-5 (poison fills own all
// slots). The body is idempotent (pure function of x,wgt -> same out values),
// so repeating it 3x in one dispatch is bit-identical and pushes the dispatch
// to ~75us > 42.6us -> full counters (FETCH/WRITE/MfmaUtil/VALUBusy/
// LDS_BANK_CONFLICT/Occupancy) become visible. reps is a runtime arg so the
// compiler can't specialize it away; end-of-rep barrier protects LDS restage.
// Round-13 structure unchanged otherwise:
//  - NT=512: waves 0-3 even d {0,2,4,6,8} (d=0/8: 9 MFMA, acc doubled),
//    waves 4-7 odd d {1,3,5,7}; 72 MFMA/wave.
//  - granule staging: 8 coalesced global_load_dword + 4 packed cvt +
//    1 ds_write_b128 per task.
//  - weights in LDS (flip + 0.5 folded), af = 9 ds_read_b128.
//  - compute_d<D>: all LDS offsets compile-time immediates.
// Identity: out[b,d*16+n,r,s] = sum 0.5W[n,c2,2-u,2-v]*(xa+xb)[r+u,s+v],
// xa=x[(8d-c2)%128], xb=x[(-8d-c2)%128]; mirror d'=16-d same acc.

typedef __attribute__((ext_vector_type(8))) short short8;
typedef __attribute__((ext_vector_type(4))) float floatx4;

#define NT 512
#define LCH 168                 // padded channel-slot dim (160 used)
#define SROWS 34                // cols per staged row (32..33 zero apron)
#define XSROW (SROWS * LCH)

template<int D, bool DUP>
__device__ __forceinline__ void compute_d(const char* basep, const short8 af[9],
                                          float* opbase) {
    floatx4 a0 = {0.f,0.f,0.f,0.f}, a1 = {0.f,0.f,0.f,0.f};
    floatx4 b0 = {0.f,0.f,0.f,0.f}, b1 = {0.f,0.f,0.f,0.f};
#pragma unroll
    for (int u = 0; u < 3; ++u)
#pragma unroll
        for (int v = 0; v < 3; ++v) {
            const int t = u * 3 + v;
            const short8 ba = *(const short8*)(basep +
                ((u * SROWS + v) * LCH + 8 * (8 + D)) * 2);
            if (t & 1) a1 = __builtin_amdgcn_mfma_f32_16x16x32_bf16(af[t], ba, a1, 0, 0, 0);
            else       a0 = __builtin_amdgcn_mfma_f32_16x16x32_bf16(af[t], ba, a0, 0, 0, 0);
            if (!DUP) {
                const short8 bb = *(const short8*)(basep +
                    ((u * SROWS + v) * LCH + 8 * (8 - D)) * 2);
                if (t & 1) b1 = __builtin_amdgcn_mfma_f32_16x16x32_bf16(af[t], bb, b1, 0, 0, 0);
                else       b0 = __builtin_amdgcn_mfma_f32_16x16x32_bf16(af[t], bb, b0, 0, 0, 0);
            }
        }
    floatx4 acc = a0 + a1;
    if (DUP) acc = acc + acc;          // xa==xb: 2*(0.5W*xa) = W*xa, bit-identical
    else     acc = acc + (b0 + b1);
    float* op = opbase + D * 16384;    // D*16*1024 floats
    op[0]    = acc.x;
    op[1024] = acc.y;
    op[2048] = acc.z;
    op[3072] = acc.w;
    if (D >= 1 && D <= 7) {            // mirror channel group 16-D
        float* op2 = opbase + (16 - D) * 16384;
        op2[0]    = acc.x;
        op2[1024] = acc.y;
        op2[2048] = acc.z;
        op2[3072] = acc.w;
    }
}

__global__ __launch_bounds__(NT, 2)
void fconv_mfma(const float* __restrict__ x,
                const float* __restrict__ wgt,
                float* __restrict__ out,
                int reps) {
    __shared__ __align__(16) short xs[4 * XSROW];   // 45,696 B
    __shared__ __align__(16) short wf[9 * 640];     // 11,520 B

    const int rq   = blockIdx.x;   // 0..15 : output row-pair
    const int b    = blockIdx.y;   // 0..15
    const int r0   = rq * 2;
    const int tid  = threadIdx.x;
    const int lane = tid & 63;
    const int wv   = tid >> 6;

    for (int rep = 0; rep < reps; ++rep) {

    // ---- weights -> LDS: wf[(8-k)*640 + n*40 + oct*8 + (7-j)] = 0.5*W[n][8oct+j][k]
    {
        const int n  = tid >> 5;        // 0..15
        const int c2 = tid & 31;
        const float* wb = wgt + (size_t)(n * 32 + c2) * 9;
        const int pos = n * 40 + (c2 & 24) + (7 - (c2 & 7));
#pragma unroll
        for (int k = 0; k < 9; ++k) {
            __hip_bfloat16 h = __float2bfloat16(0.5f * wb[k]);
            wf[(8 - k) * 640 + pos] = __builtin_bit_cast(short, h);
        }
    }

    // ---- stage raw x: 2560 granule tasks (lrow, col, oL), 5 per thread ----
    const float* xb_base = x + ((size_t)b << 17);
#pragma unroll
    for (int it = 0; it < 5; ++it) {
        const int idx  = wv * 320 + it * 64 + lane;   // 0..2559
        const int col  = idx & 31;
        const int rest = idx >> 5;                    // 0..79
        const int lrow = rest & 3;
        const int oL   = rest >> 2;                   // 0..19
        const int grow = r0 + lrow;
        short8 g;
        if (grow < 32) {
            float v[8];
#pragma unroll
            for (int j = 0; j < 8; ++j) {
                const int m = (oL * 8 + j - 95) & 127;   // channel (L-95) mod 128
                v[j] = xb_base[((m << 5) + grow) * 32 + col];
            }
            union { __hip_bfloat162 h2[4]; short8 s8; } u;
#pragma unroll
            for (int p = 0; p < 4; ++p)
                u.h2[p] = __float22bfloat162_rn(make_float2(v[2 * p], v[2 * p + 1]));
            g = u.s8;
        } else {
            g = short8{0, 0, 0, 0, 0, 0, 0, 0};
        }
        *(short8*)&xs[(lrow * SROWS + col) * LCH + oL * 8] = g;
    }
    // s-apron (col 32,33) zeros: 4 lrow * 2 col * 20 oL = 160 granules
    if (tid < 160) {
        const int oL   = tid % 20;
        const int rem  = tid / 20;       // 0..7
        const int lrow = rem >> 1;
        const int col  = 32 + (rem & 1);
        short8 z = {0, 0, 0, 0, 0, 0, 0, 0};
        *(short8*)&xs[(lrow * SROWS + col) * LCH + oL * 8] = z;
    }

    __syncthreads();

    // ---- A fragments: 9 ds_read_b128 ----
    const int n = lane & 15;      // filter row / D col lane
    const int q = lane >> 4;      // k-octet
    short8 af[9];
#pragma unroll
    for (int t = 0; t < 9; ++t)
        af[t] = *(const short8*)&wf[t * 640 + n * 40 + q * 8];

    // ---- compute: wave -> (row lr, col-half sh), d-group dg ----
    const int tile = wv & 3;
    const int lr   = tile >> 1;
    const int sh   = tile & 1;
    const int s0   = sh << 4;
    const int dg   = wv >> 2;     // 0: even d, 1: odd d

    // lane base (non-negative): col part + 8*(3-q); window imm uses 8*(8 +/- D)
    const char* basep = (const char*)xs +
        ((lr * SROWS + s0 + n) * LCH + 8 * (3 - q)) * 2;
    float* opbase = out + ((size_t)((b * 256 + q * 4) * 32 + (r0 + lr)) << 5) + s0 + n;

    if (dg == 0) {
        compute_d<0, true >(basep, af, opbase);
        compute_d<2, false>(basep, af, opbase);
        compute_d<4, false>(basep, af, opbase);
        compute_d<6, false>(basep, af, opbase);
        compute_d<8, true >(basep, af, opbase);
    } else {
        compute_d<1, false>(basep, af, opbase);
        compute_d<3, false>(basep, af, opbase);
        compute_d<5, false>(basep, af, opbase);
        compute_d<7, false>(basep, af, opbase);
    }

    __syncthreads();   // protect LDS restage of next rep
    }                  // rep loop
}

extern "C" void kernel_launch(void* const* d_in, const int* in_sizes, int n_in,
                              void* d_out, int out_size, void* d_ws, size_t ws_size,
                              hipStream_t stream) {
    const float* x   = (const float*)d_in[0];   // (16,128,32,32) fp32
    const float* wgt = (const float*)d_in[1];   // (16,32,3,3)   fp32
    float* out = (float*)d_out;                 // (16,256,32,32) fp32
    (void)in_sizes; (void)n_in; (void)out_size; (void)d_ws; (void)ws_size;

    fconv_mfma<<<dim3(16, 16), dim3(NT), 0, stream>>>(x, wgt, out, 3);
}

// Round 10
// 71.244 us; speedup vs baseline: 1.3814x; 1.3814x over previous
//
#include <hip/hip_runtime.h>
#include <hip/hip_bf16.h>

// FConv2d, round 15 (2nd resubmit; r8/r9 acquisition timeouts — no data):
// occupancy restructure based on r14 diagnostic (warm rep ~14us, cold
// premium ~11us => cold-miss latency-bound at 1 block/CU, no overlap).
//  - ONE output row per block: grid (32,16) = 512 blocks = 2 blocks/CU
//    (LDS 45.8KB x2 = 91.6 < 160KB; __launch_bounds__(512,4) caps VGPR<=128).
//  - stage 3 input rows (r..r+2); wave wv: col-half = wv&1, d-quad = wv>>1,
//    quads {0,4,8},{2,6},{1,5},{3,7} -> exactly 36 MFMA every wave.
//  - staging/LDS layout, fragment pairing, window immediates, store
//    addressing IDENTICAL to verified r13.
// Identity: out[b,d*16+n,r,s] = sum 0.5W[n,c2,2-u,2-v]*(xa+xb)[r+u,s+v],
// xa=x[(8d-c2)%128], xb=x[(-8d-c2)%128]; mirror d'=16-d same acc;
// d=0/8: xa==xb -> 9 MFMA, acc doubled (bit-identical).
// Fragment pairing (r12-verified): af[t][j]=0.5W[n][8q+7-j][8-t] with
// B-window L0 = 8*(11 +/- d - q).

typedef __attribute__((ext_vector_type(8))) short short8;
typedef __attribute__((ext_vector_type(4))) float floatx4;

#define NT 512
#define LCH 168                 // padded channel-slot dim (160 used)
#define SROWS 34                // cols per staged row (32..33 zero apron)
#define XSROW (SROWS * LCH)

template<int D, bool DUP>
__device__ __forceinline__ void compute_d(const char* basep, const short8 af[9],
                                          float* opbase) {
    floatx4 a0 = {0.f,0.f,0.f,0.f}, a1 = {0.f,0.f,0.f,0.f};
    floatx4 b0 = {0.f,0.f,0.f,0.f}, b1 = {0.f,0.f,0.f,0.f};
#pragma unroll
    for (int u = 0; u < 3; ++u)
#pragma unroll
        for (int v = 0; v < 3; ++v) {
            const int t = u * 3 + v;
            const short8 ba = *(const short8*)(basep +
                ((u * SROWS + v) * LCH + 8 * (8 + D)) * 2);
            if (t & 1) a1 = __builtin_amdgcn_mfma_f32_16x16x32_bf16(af[t], ba, a1, 0, 0, 0);
            else       a0 = __builtin_amdgcn_mfma_f32_16x16x32_bf16(af[t], ba, a0, 0, 0, 0);
            if (!DUP) {
                const short8 bb = *(const short8*)(basep +
                    ((u * SROWS + v) * LCH + 8 * (8 - D)) * 2);
                if (t & 1) b1 = __builtin_amdgcn_mfma_f32_16x16x32_bf16(af[t], bb, b1, 0, 0, 0);
                else       b0 = __builtin_amdgcn_mfma_f32_16x16x32_bf16(af[t], bb, b0, 0, 0, 0);
            }
        }
    floatx4 acc = a0 + a1;
    if (DUP) acc = acc + acc;          // xa==xb: 2*(0.5W*xa) = W*xa, bit-identical
    else     acc = acc + (b0 + b1);
    float* op = opbase + D * 16384;    // D*16*1024 floats
    op[0]    = acc.x;
    op[1024] = acc.y;
    op[2048] = acc.z;
    op[3072] = acc.w;
    if (D >= 1 && D <= 7) {            // mirror channel group 16-D
        float* op2 = opbase + (16 - D) * 16384;
        op2[0]    = acc.x;
        op2[1024] = acc.y;
        op2[2048] = acc.z;
        op2[3072] = acc.w;
    }
}

__global__ __launch_bounds__(NT, 4)
void fconv_mfma(const float* __restrict__ x,
                const float* __restrict__ wgt,
                float* __restrict__ out) {
    __shared__ __align__(16) short xs[3 * XSROW];   // 34,272 B
    __shared__ __align__(16) short wf[9 * 640];     // 11,520 B

    const int r    = blockIdx.x;   // 0..31 : output row
    const int b    = blockIdx.y;   // 0..15
    const int tid  = threadIdx.x;
    const int lane = tid & 63;
    const int wv   = tid >> 6;

    // ---- weights -> LDS: wf[(8-k)*640 + n*40 + oct*8 + (7-j)] = 0.5*W[n][8oct+j][k]
    {
        const int n  = tid >> 5;        // 0..15
        const int c2 = tid & 31;
        const float* wb = wgt + (size_t)(n * 32 + c2) * 9;
        const int pos = n * 40 + (c2 & 24) + (7 - (c2 & 7));
#pragma unroll
        for (int k = 0; k < 9; ++k) {
            __hip_bfloat16 h = __float2bfloat16(0.5f * wb[k]);
            wf[(8 - k) * 640 + pos] = __builtin_bit_cast(short, h);
        }
    }

    // ---- stage raw x rows r..r+2: 1920 granule tasks (lrow, col, oL) ----
    const float* xb_base = x + ((size_t)b << 17);
#pragma unroll
    for (int it = 0; it < 4; ++it) {
        const int idx = it * NT + tid;            // 0..2047
        if (idx < 1920) {
            const int col  = idx & 31;
            const int rest = idx >> 5;            // 0..59
            const int oL   = rest / 3;            // 0..19
            const int lrow = rest - oL * 3;       // 0..2
            const int grow = r + lrow;
            short8 g;
            if (grow < 32) {
                float v[8];
#pragma unroll
                for (int j = 0; j < 8; ++j) {
                    const int m = (oL * 8 + j - 95) & 127;   // channel (L-95) mod 128
                    v[j] = xb_base[((m << 5) + grow) * 32 + col];
                }
                union { __hip_bfloat162 h2[4]; short8 s8; } u;
#pragma unroll
                for (int p = 0; p < 4; ++p)
                    u.h2[p] = __float22bfloat162_rn(make_float2(v[2 * p], v[2 * p + 1]));
                g = u.s8;
            } else {
                g = short8{0, 0, 0, 0, 0, 0, 0, 0};
            }
            *(short8*)&xs[(lrow * SROWS + col) * LCH + oL * 8] = g;
        }
    }
    // s-apron (col 32,33) zeros: 3 lrow * 2 col * 20 oL = 120 granules
    if (tid < 120) {
        const int oL   = tid % 20;
        const int rem  = tid / 20;       // 0..5
        const int lrow = rem >> 1;
        const int col  = 32 + (rem & 1);
        short8 z = {0, 0, 0, 0, 0, 0, 0, 0};
        *(short8*)&xs[(lrow * SROWS + col) * LCH + oL * 8] = z;
    }

    __syncthreads();

    // ---- A fragments: 9 ds_read_b128 ----
    const int n = lane & 15;      // filter row / D col lane
    const int q = lane >> 4;      // k-octet
    short8 af[9];
#pragma unroll
    for (int t = 0; t < 9; ++t)
        af[t] = *(const short8*)&wf[t * 640 + n * 40 + q * 8];

    // ---- compute: wave -> (col-half, d-quad) ----
    const int half = wv & 1;
    const int dq   = wv >> 1;     // 0..3
    const int s0   = half << 4;

    // lane base (non-negative): col part + 8*(3-q); window imm uses 8*(8 +/- D)
    const char* basep = (const char*)xs + ((s0 + n) * LCH + 8 * (3 - q)) * 2;
    float* opbase = out + ((size_t)((b * 256 + q * 4) * 32 + r) << 5) + s0 + n;

    if (dq == 0) {
        compute_d<0, true >(basep, af, opbase);   // 9 MFMA
        compute_d<4, false>(basep, af, opbase);   // 18
        compute_d<8, true >(basep, af, opbase);   // 9   -> 36
    } else if (dq == 1) {
        compute_d<2, false>(basep, af, opbase);
        compute_d<6, false>(basep, af, opbase);   // 36
    } else if (dq == 2) {
        compute_d<1, false>(basep, af, opbase);
        compute_d<5, false>(basep, af, opbase);   // 36
    } else {
        compute_d<3, false>(basep, af, opbase);
        compute_d<7, false>(basep, af, opbase);   // 36
    }
}

extern "C" void kernel_launch(void* const* d_in, const int* in_sizes, int n_in,
                              void* d_out, int out_size, void* d_ws, size_t ws_size,
                              hipStream_t stream) {
    const float* x   = (const float*)d_in[0];   // (16,128,32,32) fp32
    const float* wgt = (const float*)d_in[1];   // (16,32,3,3)   fp32
    float* out = (float*)d_out;                 // (16,256,32,32) fp32
    (void)in_sizes; (void)n_in; (void)out_size; (void)d_ws; (void)ws_size;

    fconv_mfma<<<dim3(32, 16), dim3(NT), 0, stream>>>(x, wgt, out);
}